// Round 1
// baseline (62230.457 us; speedup 1.0000x reference)
//
#include <hip/hip_runtime.h>
#include <stdint.h>

#define NROWS 32768
#define HALF_D 256       // each of real/imag halves
#define DTOT 512
#define KSYN 1024
#define KSEM 4096

// ---------- helpers ----------
__device__ __forceinline__ unsigned int fkey(float f) {
    // monotone map float -> u32 (increasing), so min over key == min over float
    unsigned int u = __float_as_uint(f);
    return (u & 0x80000000u) ? ~u : (u | 0x80000000u);
}

static const float ONE_M = (float)(1.0 - 0.99);
static const float LOG2_099 = (float)(-0.014499569695115089); // log2(0.99)

// ---------- z concat: [N,256]+[N,256] -> [N,512] contiguous ----------
__global__ void zcat_kernel(const float* __restrict__ re, const float* __restrict__ im,
                            float* __restrict__ dst) {
    int i = blockIdx.x * 256 + threadIdx.x;     // i in [0, NROWS*128)
    int n = i >> 7, q = i & 127;
    const float* src = (q < 64) ? (re + (size_t)n * HALF_D + q * 4)
                                : (im + (size_t)n * HALF_D + (q - 64) * 4);
    *(float4*)(dst + (size_t)n * DTOT + q * 4) = *(const float4*)src;
}

// ---------- codebook squared norms ----------
__global__ void cnorm_kernel(const float* __restrict__ cb, float* __restrict__ cnorm) {
    int k = blockIdx.x;
    int lane = threadIdx.x;                 // 64 lanes
    const float* row = cb + (size_t)k * DTOT + lane * 8;
    float4 a = *(const float4*)row;
    float4 b = *(const float4*)(row + 4);
    float s = a.x*a.x + a.y*a.y + a.z*a.z + a.w*a.w
            + b.x*b.x + b.y*b.y + b.z*b.z + b.w*b.w;
    #pragma unroll
    for (int off = 32; off; off >>= 1) s += __shfl_down(s, off, 64);
    if (lane == 0) cnorm[k] = s;
}

// ---------- argmin GEMM: 128 rows x 128 codes per block, D-chunks of 32 ----------
#define BM 128
#define BK 128
#define DC 32
#define LSTR 36   // pad 32 -> 36 floats (144 B rows: 16B-aligned, 2-way banks = free)

// waves_per_eu pinned to 3: VGPR budget 168/wave so the ~145-reg live set
// (acc 64 + prefetch tz/tk 32 + za 32 + addressing) allocates WITHOUT spilling.
// The previous build allocated exactly 128 (4-wave tier) and spilled in the
// inner loop: 78 GB scratch writes + 41 GB reloads per sem dispatch, 96% stall.
// 3 blocks/CU x 36 KB LDS = 108 KB <= 160 KB.
__global__ __launch_bounds__(256) __attribute__((amdgpu_waves_per_eu(3, 3)))
void argmin_kernel(const float* __restrict__ z,   // [NROWS,512] contiguous
                   const float* __restrict__ cb,  // [K,512]
                   const float* __restrict__ cnorm,
                   unsigned long long* __restrict__ minpack, int K) {
    __shared__ float zs[BM * LSTR];
    __shared__ float ks[BK * LSTR];
    const int t = threadIdx.x;
    const int rowBase = blockIdx.y * BM;
    const int kBase = blockIdx.x * BK;
    const int tx = t & 15, ty = t >> 4;

    // staging geometry: thread t, sub-iter u handles float4 chunk v = t + 256u
    // of the 128x32 tile: row = (t>>3) + 32u, d4 = (t&7)*4.
    // 32-bit float-index offsets (z <= 64 MB, cb <= 8 MB -> fits u32).
    const int srow = t >> 3, sd4 = (t & 7) * 4;
    const unsigned zoff = (unsigned)(rowBase + srow) * DTOT + sd4;
    const unsigned koff = (unsigned)(kBase + srow) * DTOT + sd4;
    const int lw = srow * LSTR + sd4;            // LDS write idx; u-stride 32*LSTR

    float acc[8][8];
    #pragma unroll
    for (int i = 0; i < 8; i++)
        #pragma unroll
        for (int j = 0; j < 8; j++) acc[i][j] = 0.0f;

    // prefetch chunk 0 into registers (T14: issue early, write after barrier)
    float4 tz[4], tk[4];
    #pragma unroll
    for (int u = 0; u < 4; u++) {
        tz[u] = *(const float4*)(z + zoff + u * (32 * DTOT));
        tk[u] = *(const float4*)(cb + koff + u * (32 * DTOT));
    }

    for (int dc = 0; dc < DTOT; dc += DC) {
        __syncthreads();                 // previous chunk's LDS reads complete
        #pragma unroll
        for (int u = 0; u < 4; u++) {
            *(float4*)&zs[lw + u * (32 * LSTR)] = tz[u];
            *(float4*)&ks[lw + u * (32 * LSTR)] = tk[u];
        }
        __syncthreads();                 // chunk dc visible
        if (dc + DC < DTOT) {
            // issue next chunk's global loads now; latency hides under compute
            #pragma unroll
            for (int u = 0; u < 4; u++) {
                tz[u] = *(const float4*)(z + zoff + (dc + DC) + u * (32 * DTOT));
                tk[u] = *(const float4*)(cb + koff + (dc + DC) + u * (32 * DTOT));
            }
        }
        #pragma unroll
        for (int dd = 0; dd < DC; dd += 4) {
            float4 za[8];
            #pragma unroll
            for (int i = 0; i < 8; i++)
                za[i] = *(const float4*)&zs[(ty + 16 * i) * LSTR + dd];
            #pragma unroll
            for (int j = 0; j < 8; j++) {
                float4 ca = *(const float4*)&ks[(tx + 16 * j) * LSTR + dd];
                #pragma unroll
                for (int i = 0; i < 8; i++)
                    acc[i][j] += za[i].x*ca.x + za[i].y*ca.y + za[i].z*ca.z + za[i].w*ca.w;
            }
        }
    }

    float cn[8];
    #pragma unroll
    for (int j = 0; j < 8; j++) cn[j] = cnorm[kBase + tx + 16 * j];

    #pragma unroll
    for (int i = 0; i < 8; i++) {
        unsigned long long best = ~0ull;
        #pragma unroll
        for (int j = 0; j < 8; j++) {
            float s = cn[j] - 2.0f * acc[i][j];
            unsigned long long p = ((unsigned long long)fkey(s) << 32)
                                 | (unsigned int)(kBase + tx + 16 * j);
            if (p < best) best = p;
        }
        #pragma unroll
        for (int off = 8; off; off >>= 1) {
            unsigned long long o = __shfl_xor(best, off, 16);
            if (o < best) best = o;
        }
        if (tx == 0) atomicMin(&minpack[rowBase + ty + 16 * i], best);
    }
}

// ---------- extract idx (as float) ----------
__global__ void extract_kernel(const unsigned long long* __restrict__ mp,
                               float* __restrict__ out_idx) {
    int i = blockIdx.x * 256 + threadIdx.x;
    out_idx[i] = (float)(unsigned int)(mp[i] & 0xffffffffull);
}

// ---------- per-row scatter: zq write, loss, counts, pair counts, embed_sum ----------
__launch_bounds__(256)
__global__ void scatter_kernel(const float* __restrict__ zr, const float* __restrict__ zi,
                               const float* __restrict__ cb, const int* __restrict__ prev_idx,
                               const float* __restrict__ idx_f,
                               float* __restrict__ zq, float* __restrict__ embed,
                               float* __restrict__ counts, float* __restrict__ adj,
                               double* __restrict__ loss_slots, int K) {
    const int wave = threadIdx.x >> 6, lane = threadIdx.x & 63;
    const int n = blockIdx.x * 4 + wave;
    const int idx = (int)idx_f[n];
    const float* zrrow = zr + (size_t)n * HALF_D;
    const float* zirow = zi + (size_t)n * HALF_D;
    const float* crow = cb + (size_t)idx * DTOT;
    float* zqrow = zq + (size_t)n * DTOT;
    const int d0 = lane * 4;

    float4 z0 = *(const float4*)(zrrow + d0);
    float4 z1 = *(const float4*)(zirow + d0);
    float4 c0 = *(const float4*)(crow + d0);
    float4 c1 = *(const float4*)(crow + HALF_D + d0);

    float4 q0, q1;
    q0.x = z0.x + (c0.x - z0.x); q0.y = z0.y + (c0.y - z0.y);
    q0.z = z0.z + (c0.z - z0.z); q0.w = z0.w + (c0.w - z0.w);
    q1.x = z1.x + (c1.x - z1.x); q1.y = z1.y + (c1.y - z1.y);
    q1.z = z1.z + (c1.z - z1.z); q1.w = z1.w + (c1.w - z1.w);
    *(float4*)(zqrow + d0) = q0;
    *(float4*)(zqrow + HALF_D + d0) = q1;

    float dx, lsum = 0.0f;
    dx = c0.x - z0.x; lsum += dx * dx;   dx = c0.y - z0.y; lsum += dx * dx;
    dx = c0.z - z0.z; lsum += dx * dx;   dx = c0.w - z0.w; lsum += dx * dx;
    dx = c1.x - z1.x; lsum += dx * dx;   dx = c1.y - z1.y; lsum += dx * dx;
    dx = c1.z - z1.z; lsum += dx * dx;   dx = c1.w - z1.w; lsum += dx * dx;

    float* erow = embed + (size_t)idx * DTOT;
    atomicAdd(erow + d0 + 0, z0.x); atomicAdd(erow + d0 + 1, z0.y);
    atomicAdd(erow + d0 + 2, z0.z); atomicAdd(erow + d0 + 3, z0.w);
    atomicAdd(erow + HALF_D + d0 + 0, z1.x); atomicAdd(erow + HALF_D + d0 + 1, z1.y);
    atomicAdd(erow + HALF_D + d0 + 2, z1.z); atomicAdd(erow + HALF_D + d0 + 3, z1.w);

    #pragma unroll
    for (int off = 32; off; off >>= 1) lsum += __shfl_down(lsum, off, 64);
    if (lane == 0) {
        atomicAdd(&loss_slots[blockIdx.x & 255], (double)lsum);
        atomicAdd(&counts[idx], 1.0f);
        int p = prev_idx[n];
        atomicAdd(&adj[(size_t)p * K + idx], 1.0f);
    }
}

// ---------- cluster-size EMA + cs normalizer ----------
__global__ void cs_kernel(const float* __restrict__ cl, const float* __restrict__ counts,
                          float* __restrict__ cs, int K) {
    __shared__ float red[1024];
    int t = threadIdx.x;
    float s = 0.0f;
    for (int k = t; k < K; k += 1024) {
        float v = cl[k] * 0.99f + ONE_M * counts[k];
        cs[k] = v;
        s += v;
    }
    red[t] = s;
    __syncthreads();
    for (int off = 512; off; off >>= 1) {
        if (t < off) red[t] += red[t + off];
        __syncthreads();
    }
    float n = red[0];
    float keps = (float)((double)K * 1e-6);
    for (int k = t; k < K; k += 1024)
        cs[k] = (cs[k] + 1e-6f) / (n + keps) * n;
}

// ---------- codebook finalize: cb = (avg*0.99 + 0.01*embed_sum)/cs ----------
__global__ void cbfin_kernel(const float* __restrict__ avg, const float* __restrict__ cs,
                             float* __restrict__ cbout, int total) {
    int i = blockIdx.x * 256 + threadIdx.x;
    if (i < total) {
        float v = avg[i] * 0.99f + ONE_M * cbout[i];   // cbout currently holds embed_sum
        cbout[i] = v / cs[i >> 9];
    }
}

// ---------- adjacency decay transform (in-place over pair counts) ----------
__global__ void adj_kernel(const float* __restrict__ adj_in, float* __restrict__ adjout,
                           int total) {
    int i = blockIdx.x * 256 + threadIdx.x;
    if (i < total) {
        float c = adjout[i];                 // pair count
        float p = exp2f(c * LOG2_099);       // 0.99^c
        adjout[i] = adj_in[i] * p + (1.0f - p) / ONE_M;
    }
}

// ---------- loss finalize ----------
__global__ void loss_kernel(const double* __restrict__ slots, float* __restrict__ out) {
    __shared__ double red[256];
    int t = threadIdx.x;
    red[t] = slots[t] + slots[256 + t];
    __syncthreads();
    for (int off = 128; off; off >>= 1) {
        if (t < off) red[t] += red[t + off];
        __syncthreads();
    }
    if (t == 0) out[0] = (float)(1.25 * red[0] / 16777216.0);
}

extern "C" void kernel_launch(void* const* d_in, const int* in_sizes, int n_in,
                              void* d_out, int out_size, void* d_ws, size_t ws_size,
                              hipStream_t stream) {
    const float* zfr = (const float*)d_in[0];
    const float* zfi = (const float*)d_in[1];
    const float* zsr = (const float*)d_in[2];
    const float* zsi = (const float*)d_in[3];
    const int* prev_syn = (const int*)d_in[4];
    const int* prev_sem = (const int*)d_in[5];
    const float* cb_syn = (const float*)d_in[6];
    const float* cb_sem = (const float*)d_in[7];
    const float* cl_syn = (const float*)d_in[8];
    const float* avg_syn = (const float*)d_in[9];
    const float* cl_sem = (const float*)d_in[10];
    const float* avg_sem = (const float*)d_in[11];
    const float* adj_syn_in = (const float*)d_in[12];
    const float* adj_sem_in = (const float*)d_in[13];

    float* out = (float*)d_out;
    size_t o = 0;
    float* zq_syn = out + o;  o += (size_t)NROWS * DTOT;
    float* zq_sem = out + o;  o += (size_t)NROWS * DTOT;
    float* loss_out = out + o; o += 1;
    float* idx_syn = out + o; o += NROWS;
    float* idx_sem = out + o; o += NROWS;
    float* cbo_syn = out + o; o += (size_t)KSYN * DTOT;
    float* cbo_sem = out + o; o += (size_t)KSEM * DTOT;
    float* adjo_syn = out + o; o += (size_t)KSYN * KSYN;
    float* adjo_sem = out + o; o += (size_t)KSEM * KSEM;

    // small scratch in ws (64 KB)
    char* ws = (char*)d_ws;
    float* counts_syn = (float*)(ws + 0);        // 1024 f32
    float* counts_sem = (float*)(ws + 4096);     // 4096 f32
    float* cs_syn     = (float*)(ws + 20480);    // 1024 f32
    float* cs_sem     = (float*)(ws + 24576);    // 4096 f32
    float* cn_syn     = (float*)(ws + 40960);    // 1024 f32
    float* cn_sem     = (float*)(ws + 45056);    // 4096 f32
    double* loss_slots = (double*)(ws + 61440);  // 256 (syn) + 256 (sem) doubles

    // zcat buffers live in the zq output regions (exact size match);
    // consumed by argmin before scatter overwrites them with zq.
    float* zcat_syn = zq_syn;
    float* zcat_sem = zq_sem;
    // minpack lives in the head of adjo_sem; adjo_sem's FLOAT offset is odd, so
    // round up to the next 8-byte boundary for the 64-bit atomics (the round-2
    // crash was a misaligned atomicMin_u64). adj memset happens AFTER extract.
    unsigned long long* mp_syn =
        (unsigned long long*)(((uintptr_t)adjo_sem + 7) & ~(uintptr_t)7);
    unsigned long long* mp_sem = mp_syn + NROWS;

    hipMemsetAsync(d_ws, 0, 65536, stream);
    hipMemsetAsync((void*)mp_syn, 0xFF, (size_t)2 * NROWS * sizeof(unsigned long long), stream);
    hipMemsetAsync((void*)cbo_syn, 0,
                   ((size_t)KSYN * DTOT + (size_t)KSEM * DTOT) * sizeof(float), stream);

    zcat_kernel<<<NROWS * 128 / 256, 256, 0, stream>>>(zfr, zfi, zcat_syn);
    zcat_kernel<<<NROWS * 128 / 256, 256, 0, stream>>>(zsr, zsi, zcat_sem);

    cnorm_kernel<<<KSYN, 64, 0, stream>>>(cb_syn, cn_syn);
    cnorm_kernel<<<KSEM, 64, 0, stream>>>(cb_sem, cn_sem);

    argmin_kernel<<<dim3(KSYN / BK, NROWS / BM), 256, 0, stream>>>(
        zcat_syn, cb_syn, cn_syn, mp_syn, KSYN);
    argmin_kernel<<<dim3(KSEM / BK, NROWS / BM), 256, 0, stream>>>(
        zcat_sem, cb_sem, cn_sem, mp_sem, KSEM);

    extract_kernel<<<NROWS / 256, 256, 0, stream>>>(mp_syn, idx_syn);
    extract_kernel<<<NROWS / 256, 256, 0, stream>>>(mp_sem, idx_sem);

    // now safe to zero the adjacency accumulators (minpack already consumed)
    hipMemsetAsync((void*)adjo_syn, 0,
                   ((size_t)KSYN * KSYN + (size_t)KSEM * KSEM) * sizeof(float), stream);

    scatter_kernel<<<NROWS / 4, 256, 0, stream>>>(
        zfr, zfi, cb_syn, prev_syn, idx_syn, zq_syn, cbo_syn, counts_syn, adjo_syn,
        loss_slots, KSYN);
    scatter_kernel<<<NROWS / 4, 256, 0, stream>>>(
        zsr, zsi, cb_sem, prev_sem, idx_sem, zq_sem, cbo_sem, counts_sem, adjo_sem,
        loss_slots + 256, KSEM);

    cs_kernel<<<1, 1024, 0, stream>>>(cl_syn, counts_syn, cs_syn, KSYN);
    cs_kernel<<<1, 1024, 0, stream>>>(cl_sem, counts_sem, cs_sem, KSEM);

    cbfin_kernel<<<(KSYN * DTOT) / 256, 256, 0, stream>>>(avg_syn, cs_syn, cbo_syn, KSYN * DTOT);
    cbfin_kernel<<<(KSEM * DTOT) / 256, 256, 0, stream>>>(avg_sem, cs_sem, cbo_sem, KSEM * DTOT);

    adj_kernel<<<(KSYN * KSYN) / 256, 256, 0, stream>>>(adj_syn_in, adjo_syn, KSYN * KSYN);
    adj_kernel<<<(KSEM * KSEM) / 256, 256, 0, stream>>>(adj_sem_in, adjo_sem, KSEM * KSEM);

    loss_kernel<<<1, 256, 0, stream>>>(loss_slots, loss_out);
}

// Round 3
// 30995.255 us; speedup vs baseline: 2.0077x; 2.0077x over previous
//
#include <hip/hip_runtime.h>
#include <stdint.h>

#define NROWS 32768
#define HALF_D 256       // each of real/imag halves
#define DTOT 512
#define KSYN 1024
#define KSEM 4096

// ---------- helpers ----------
__device__ __forceinline__ unsigned int fkey(float f) {
    // monotone map float -> u32 (increasing), so min over key == min over float
    unsigned int u = __float_as_uint(f);
    return (u & 0x80000000u) ? ~u : (u | 0x80000000u);
}

static const float ONE_M = (float)(1.0 - 0.99);
static const float LOG2_099 = (float)(-0.014499569695115089); // log2(0.99)

// ---------- z concat: [N,256]+[N,256] -> [N,512] contiguous ----------
__global__ void zcat_kernel(const float* __restrict__ re, const float* __restrict__ im,
                            float* __restrict__ dst) {
    int i = blockIdx.x * 256 + threadIdx.x;     // i in [0, NROWS*128)
    int n = i >> 7, q = i & 127;
    const float* src = (q < 64) ? (re + (size_t)n * HALF_D + q * 4)
                                : (im + (size_t)n * HALF_D + (q - 64) * 4);
    *(float4*)(dst + (size_t)n * DTOT + q * 4) = *(const float4*)src;
}

// ---------- codebook squared norms ----------
__global__ void cnorm_kernel(const float* __restrict__ cb, float* __restrict__ cnorm) {
    int k = blockIdx.x;
    int lane = threadIdx.x;                 // 64 lanes
    const float* row = cb + (size_t)k * DTOT + lane * 8;
    float4 a = *(const float4*)row;
    float4 b = *(const float4*)(row + 4);
    float s = a.x*a.x + a.y*a.y + a.z*a.z + a.w*a.w
            + b.x*b.x + b.y*b.y + b.z*b.z + b.w*b.w;
    #pragma unroll
    for (int off = 32; off; off >>= 1) s += __shfl_down(s, off, 64);
    if (lane == 0) cnorm[k] = s;
}

// ---------- argmin GEMM: 128 rows x 128 codes per block, D-chunks of 32 ----------
// Staging via global_load_lds (zero staging VGPRs -> no spill), LDS double-
// buffered. One __syncthreads() per chunk (compiler emits the vmcnt(0) drain
// before s_barrier — verified m97 structure); next-chunk DMA issued right
// after the barrier so it flies under the current chunk's compute.
// LDS is LINEAR [128][32] (global_load_lds writes base+lane*16); bank
// conflicts handled by the XOR swizzle applied on BOTH the per-lane global
// source column and the ds_read index (both-sides-or-neither rule):
//   LDS[row][c4] holds global[row][c4 ^ (row&7)]
#define BM 128
#define BK 128
#define DC 32

typedef const __attribute__((address_space(1))) unsigned int gu32;
typedef __attribute__((address_space(3))) unsigned int lu32;

__device__ __forceinline__ void gld_lds16(const float* g, float* l) {
    __builtin_amdgcn_global_load_lds((gu32*)g, (lu32*)l, 16, 0, 0);
}

__global__ __launch_bounds__(256)
void argmin_kernel(const float* __restrict__ z,   // [NROWS,512] contiguous
                   const float* __restrict__ cb,  // [K,512]
                   const float* __restrict__ cnorm,
                   unsigned long long* __restrict__ minpack, int K) {
    __shared__ float zs[2][BM * DC];   // 2 x 16 KB
    __shared__ float ks[2][BK * DC];   // 2 x 16 KB
    const int t = threadIdx.x;
    const int w = t >> 6;              // wave id 0..3
    const int l = t & 63;              // lane
    const int rowBase = blockIdx.y * BM;
    const int kBase = blockIdx.x * BK;
    const int tx = t & 15, ty = t >> 4;

    // Staging geometry: wave w, issue u covers tile rows w*8 + 32u + (l>>3);
    // lane l's 16B lands at LDS slot c4 = l&7 of that row. Source column is
    // pre-permuted so the LDS swizzle invariant holds:
    //   c4src = (l&7) ^ (l>>3)     [row&7 == l>>3 since (w*8 + 32u) % 8 == 0]
    const int srow = l >> 3;
    const int sc4 = (l & 7) ^ srow;
    const float* zg = z + (size_t)(rowBase + w * 8 + srow) * DTOT + sc4 * 4;
    const float* kg = cb + (size_t)(kBase + w * 8 + srow) * DTOT + sc4 * 4;

    float acc[8][8];
    #pragma unroll
    for (int i = 0; i < 8; i++)
        #pragma unroll
        for (int j = 0; j < 8; j++) acc[i][j] = 0.0f;

    // prologue: stage chunk 0 into buffer 0
    #pragma unroll
    for (int u = 0; u < 4; u++) {
        gld_lds16(zg + u * (32 * DTOT), &zs[0][(w * 8 + u * 32) * DC]);
        gld_lds16(kg + u * (32 * DTOT), &ks[0][(w * 8 + u * 32) * DC]);
    }

    int buf = 0;
    for (int dc = 0; dc < DTOT; dc += DC, buf ^= 1) {
        // drains the staging of `buf` (compiler inserts vmcnt(0) before the
        // barrier) and ensures every wave finished computing on buf^1
        __syncthreads();
        if (dc + DC < DTOT) {
            // issue next chunk into the other buffer; overlaps with compute
            #pragma unroll
            for (int u = 0; u < 4; u++) {
                gld_lds16(zg + (dc + DC) + u * (32 * DTOT),
                          &zs[buf ^ 1][(w * 8 + u * 32) * DC]);
                gld_lds16(kg + (dc + DC) + u * (32 * DTOT),
                          &ks[buf ^ 1][(w * 8 + u * 32) * DC]);
            }
        }
        #pragma unroll
        for (int dd = 0; dd < DC; dd += 4) {
            const int xz4 = ((dd >> 2) ^ (ty & 7)) * 4;   // read-side XOR (z rows)
            const int xk4 = ((dd >> 2) ^ (tx & 7)) * 4;   // read-side XOR (cb rows)
            float4 za[8];
            #pragma unroll
            for (int i = 0; i < 8; i++)
                za[i] = *(const float4*)&zs[buf][(ty + 16 * i) * DC + xz4];
            #pragma unroll
            for (int j = 0; j < 8; j++) {
                float4 ca = *(const float4*)&ks[buf][(tx + 16 * j) * DC + xk4];
                #pragma unroll
                for (int i = 0; i < 8; i++)
                    acc[i][j] += za[i].x*ca.x + za[i].y*ca.y + za[i].z*ca.z + za[i].w*ca.w;
            }
        }
    }

    float cn[8];
    #pragma unroll
    for (int j = 0; j < 8; j++) cn[j] = cnorm[kBase + tx + 16 * j];

    #pragma unroll
    for (int i = 0; i < 8; i++) {
        unsigned long long best = ~0ull;
        #pragma unroll
        for (int j = 0; j < 8; j++) {
            float s = cn[j] - 2.0f * acc[i][j];
            unsigned long long p = ((unsigned long long)fkey(s) << 32)
                                 | (unsigned int)(kBase + tx + 16 * j);
            if (p < best) best = p;
        }
        #pragma unroll
        for (int off = 8; off; off >>= 1) {
            unsigned long long o = __shfl_xor(best, off, 16);
            if (o < best) best = o;
        }
        if (tx == 0) atomicMin(&minpack[rowBase + ty + 16 * i], best);
    }
}

// ---------- extract idx (as float) ----------
__global__ void extract_kernel(const unsigned long long* __restrict__ mp,
                               float* __restrict__ out_idx) {
    int i = blockIdx.x * 256 + threadIdx.x;
    out_idx[i] = (float)(unsigned int)(mp[i] & 0xffffffffull);
}

// ---------- per-row scatter: zq write, loss, counts, pair counts, embed_sum ----------
__launch_bounds__(256)
__global__ void scatter_kernel(const float* __restrict__ zr, const float* __restrict__ zi,
                               const float* __restrict__ cb, const int* __restrict__ prev_idx,
                               const float* __restrict__ idx_f,
                               float* __restrict__ zq, float* __restrict__ embed,
                               float* __restrict__ counts, float* __restrict__ adj,
                               double* __restrict__ loss_slots, int K) {
    const int wave = threadIdx.x >> 6, lane = threadIdx.x & 63;
    const int n = blockIdx.x * 4 + wave;
    const int idx = (int)idx_f[n];
    const float* zrrow = zr + (size_t)n * HALF_D;
    const float* zirow = zi + (size_t)n * HALF_D;
    const float* crow = cb + (size_t)idx * DTOT;
    float* zqrow = zq + (size_t)n * DTOT;
    const int d0 = lane * 4;

    float4 z0 = *(const float4*)(zrrow + d0);
    float4 z1 = *(const float4*)(zirow + d0);
    float4 c0 = *(const float4*)(crow + d0);
    float4 c1 = *(const float4*)(crow + HALF_D + d0);

    float4 q0, q1;
    q0.x = z0.x + (c0.x - z0.x); q0.y = z0.y + (c0.y - z0.y);
    q0.z = z0.z + (c0.z - z0.z); q0.w = z0.w + (c0.w - z0.w);
    q1.x = z1.x + (c1.x - z1.x); q1.y = z1.y + (c1.y - z1.y);
    q1.z = z1.z + (c1.z - z1.z); q1.w = z1.w + (c1.w - z1.w);
    *(float4*)(zqrow + d0) = q0;
    *(float4*)(zqrow + HALF_D + d0) = q1;

    float dx, lsum = 0.0f;
    dx = c0.x - z0.x; lsum += dx * dx;   dx = c0.y - z0.y; lsum += dx * dx;
    dx = c0.z - z0.z; lsum += dx * dx;   dx = c0.w - z0.w; lsum += dx * dx;
    dx = c1.x - z1.x; lsum += dx * dx;   dx = c1.y - z1.y; lsum += dx * dx;
    dx = c1.z - z1.z; lsum += dx * dx;   dx = c1.w - z1.w; lsum += dx * dx;

    float* erow = embed + (size_t)idx * DTOT;
    atomicAdd(erow + d0 + 0, z0.x); atomicAdd(erow + d0 + 1, z0.y);
    atomicAdd(erow + d0 + 2, z0.z); atomicAdd(erow + d0 + 3, z0.w);
    atomicAdd(erow + HALF_D + d0 + 0, z1.x); atomicAdd(erow + HALF_D + d0 + 1, z1.y);
    atomicAdd(erow + HALF_D + d0 + 2, z1.z); atomicAdd(erow + HALF_D + d0 + 3, z1.w);

    #pragma unroll
    for (int off = 32; off; off >>= 1) lsum += __shfl_down(lsum, off, 64);
    if (lane == 0) {
        atomicAdd(&loss_slots[blockIdx.x & 255], (double)lsum);
        atomicAdd(&counts[idx], 1.0f);
        int p = prev_idx[n];
        atomicAdd(&adj[(size_t)p * K + idx], 1.0f);
    }
}

// ---------- cluster-size EMA + cs normalizer ----------
__global__ void cs_kernel(const float* __restrict__ cl, const float* __restrict__ counts,
                          float* __restrict__ cs, int K) {
    __shared__ float red[1024];
    int t = threadIdx.x;
    float s = 0.0f;
    for (int k = t; k < K; k += 1024) {
        float v = cl[k] * 0.99f + ONE_M * counts[k];
        cs[k] = v;
        s += v;
    }
    red[t] = s;
    __syncthreads();
    for (int off = 512; off; off >>= 1) {
        if (t < off) red[t] += red[t + off];
        __syncthreads();
    }
    float n = red[0];
    float keps = (float)((double)K * 1e-6);
    for (int k = t; k < K; k += 1024)
        cs[k] = (cs[k] + 1e-6f) / (n + keps) * n;
}

// ---------- codebook finalize: cb = (avg*0.99 + 0.01*embed_sum)/cs ----------
__global__ void cbfin_kernel(const float* __restrict__ avg, const float* __restrict__ cs,
                             float* __restrict__ cbout, int total) {
    int i = blockIdx.x * 256 + threadIdx.x;
    if (i < total) {
        float v = avg[i] * 0.99f + ONE_M * cbout[i];   // cbout currently holds embed_sum
        cbout[i] = v / cs[i >> 9];
    }
}

// ---------- adjacency decay transform (in-place over pair counts) ----------
__global__ void adj_kernel(const float* __restrict__ adj_in, float* __restrict__ adjout,
                           int total) {
    int i = blockIdx.x * 256 + threadIdx.x;
    if (i < total) {
        float c = adjout[i];                 // pair count
        float p = exp2f(c * LOG2_099);       // 0.99^c
        adjout[i] = adj_in[i] * p + (1.0f - p) / ONE_M;
    }
}

// ---------- loss finalize ----------
__global__ void loss_kernel(const double* __restrict__ slots, float* __restrict__ out) {
    __shared__ double red[256];
    int t = threadIdx.x;
    red[t] = slots[t] + slots[256 + t];
    __syncthreads();
    for (int off = 128; off; off >>= 1) {
        if (t < off) red[t] += red[t + off];
        __syncthreads();
    }
    if (t == 0) out[0] = (float)(1.25 * red[0] / 16777216.0);
}

extern "C" void kernel_launch(void* const* d_in, const int* in_sizes, int n_in,
                              void* d_out, int out_size, void* d_ws, size_t ws_size,
                              hipStream_t stream) {
    const float* zfr = (const float*)d_in[0];
    const float* zfi = (const float*)d_in[1];
    const float* zsr = (const float*)d_in[2];
    const float* zsi = (const float*)d_in[3];
    const int* prev_syn = (const int*)d_in[4];
    const int* prev_sem = (const int*)d_in[5];
    const float* cb_syn = (const float*)d_in[6];
    const float* cb_sem = (const float*)d_in[7];
    const float* cl_syn = (const float*)d_in[8];
    const float* avg_syn = (const float*)d_in[9];
    const float* cl_sem = (const float*)d_in[10];
    const float* avg_sem = (const float*)d_in[11];
    const float* adj_syn_in = (const float*)d_in[12];
    const float* adj_sem_in = (const float*)d_in[13];

    float* out = (float*)d_out;
    size_t o = 0;
    float* zq_syn = out + o;  o += (size_t)NROWS * DTOT;
    float* zq_sem = out + o;  o += (size_t)NROWS * DTOT;
    float* loss_out = out + o; o += 1;
    float* idx_syn = out + o; o += NROWS;
    float* idx_sem = out + o; o += NROWS;
    float* cbo_syn = out + o; o += (size_t)KSYN * DTOT;
    float* cbo_sem = out + o; o += (size_t)KSEM * DTOT;
    float* adjo_syn = out + o; o += (size_t)KSYN * KSYN;
    float* adjo_sem = out + o; o += (size_t)KSEM * KSEM;

    // small scratch in ws (64 KB)
    char* ws = (char*)d_ws;
    float* counts_syn = (float*)(ws + 0);        // 1024 f32
    float* counts_sem = (float*)(ws + 4096);     // 4096 f32
    float* cs_syn     = (float*)(ws + 20480);    // 1024 f32
    float* cs_sem     = (float*)(ws + 24576);    // 4096 f32
    float* cn_syn     = (float*)(ws + 40960);    // 1024 f32
    float* cn_sem     = (float*)(ws + 45056);    // 4096 f32
    double* loss_slots = (double*)(ws + 61440);  // 256 (syn) + 256 (sem) doubles

    // zcat buffers live in the zq output regions (exact size match);
    // consumed by argmin before scatter overwrites them with zq.
    float* zcat_syn = zq_syn;
    float* zcat_sem = zq_sem;
    // minpack lives in the head of adjo_sem; adjo_sem's FLOAT offset is odd, so
    // round up to the next 8-byte boundary for the 64-bit atomics (the round-2
    // crash was a misaligned atomicMin_u64). adj memset happens AFTER extract.
    unsigned long long* mp_syn =
        (unsigned long long*)(((uintptr_t)adjo_sem + 7) & ~(uintptr_t)7);
    unsigned long long* mp_sem = mp_syn + NROWS;

    hipMemsetAsync(d_ws, 0, 65536, stream);
    hipMemsetAsync((void*)mp_syn, 0xFF, (size_t)2 * NROWS * sizeof(unsigned long long), stream);
    hipMemsetAsync((void*)cbo_syn, 0,
                   ((size_t)KSYN * DTOT + (size_t)KSEM * DTOT) * sizeof(float), stream);

    zcat_kernel<<<NROWS * 128 / 256, 256, 0, stream>>>(zfr, zfi, zcat_syn);
    zcat_kernel<<<NROWS * 128 / 256, 256, 0, stream>>>(zsr, zsi, zcat_sem);

    cnorm_kernel<<<KSYN, 64, 0, stream>>>(cb_syn, cn_syn);
    cnorm_kernel<<<KSEM, 64, 0, stream>>>(cb_sem, cn_sem);

    argmin_kernel<<<dim3(KSYN / BK, NROWS / BM), 256, 0, stream>>>(
        zcat_syn, cb_syn, cn_syn, mp_syn, KSYN);
    argmin_kernel<<<dim3(KSEM / BK, NROWS / BM), 256, 0, stream>>>(
        zcat_sem, cb_sem, cn_sem, mp_sem, KSEM);

    extract_kernel<<<NROWS / 256, 256, 0, stream>>>(mp_syn, idx_syn);
    extract_kernel<<<NROWS / 256, 256, 0, stream>>>(mp_sem, idx_sem);

    // now safe to zero the adjacency accumulators (minpack already consumed)
    hipMemsetAsync((void*)adjo_syn, 0,
                   ((size_t)KSYN * KSYN + (size_t)KSEM * KSEM) * sizeof(float), stream);

    scatter_kernel<<<NROWS / 4, 256, 0, stream>>>(
        zfr, zfi, cb_syn, prev_syn, idx_syn, zq_syn, cbo_syn, counts_syn, adjo_syn,
        loss_slots, KSYN);
    scatter_kernel<<<NROWS / 4, 256, 0, stream>>>(
        zsr, zsi, cb_sem, prev_sem, idx_sem, zq_sem, cbo_sem, counts_sem, adjo_sem,
        loss_slots + 256, KSEM);

    cs_kernel<<<1, 1024, 0, stream>>>(cl_syn, counts_syn, cs_syn, KSYN);
    cs_kernel<<<1, 1024, 0, stream>>>(cl_sem, counts_sem, cs_sem, KSEM);

    cbfin_kernel<<<(KSYN * DTOT) / 256, 256, 0, stream>>>(avg_syn, cs_syn, cbo_syn, KSYN * DTOT);
    cbfin_kernel<<<(KSEM * DTOT) / 256, 256, 0, stream>>>(avg_sem, cs_sem, cbo_sem, KSEM * DTOT);

    adj_kernel<<<(KSYN * KSYN) / 256, 256, 0, stream>>>(adj_syn_in, adjo_syn, KSYN * KSYN);
    adj_kernel<<<(KSEM * KSEM) / 256, 256, 0, stream>>>(adj_sem_in, adjo_sem, KSEM * KSEM);

    loss_kernel<<<1, 256, 0, stream>>>(loss_slots, loss_out);
}

// Round 4
// 3350.766 us; speedup vs baseline: 18.5720x; 9.2502x over previous
//
#include <hip/hip_runtime.h>
#include <stdint.h>

#define NROWS 32768
#define HALF_D 256       // each of real/imag halves
#define DTOT 512
#define KSYN 1024
#define KSEM 4096

// ---------- helpers ----------
__device__ __forceinline__ unsigned int fkey(float f) {
    // monotone map float -> u32 (increasing), so min over key == min over float
    unsigned int u = __float_as_uint(f);
    return (u & 0x80000000u) ? ~u : (u | 0x80000000u);
}

static const float ONE_M = (float)(1.0 - 0.99);
static const float LOG2_099 = (float)(-0.014499569695115089); // log2(0.99)

// ---------- z concat: [N,256]+[N,256] -> [N,512] contiguous ----------
__global__ void zcat_kernel(const float* __restrict__ re, const float* __restrict__ im,
                            float* __restrict__ dst) {
    int i = blockIdx.x * 256 + threadIdx.x;     // i in [0, NROWS*128)
    int n = i >> 7, q = i & 127;
    const float* src = (q < 64) ? (re + (size_t)n * HALF_D + q * 4)
                                : (im + (size_t)n * HALF_D + (q - 64) * 4);
    *(float4*)(dst + (size_t)n * DTOT + q * 4) = *(const float4*)src;
}

// ---------- codebook squared norms ----------
__global__ void cnorm_kernel(const float* __restrict__ cb, float* __restrict__ cnorm) {
    int k = blockIdx.x;
    int lane = threadIdx.x;                 // 64 lanes
    const float* row = cb + (size_t)k * DTOT + lane * 8;
    float4 a = *(const float4*)row;
    float4 b = *(const float4*)(row + 4);
    float s = a.x*a.x + a.y*a.y + a.z*a.z + a.w*a.w
            + b.x*b.x + b.y*b.y + b.z*b.z + b.w*b.w;
    #pragma unroll
    for (int off = 32; off; off >>= 1) s += __shfl_down(s, off, 64);
    if (lane == 0) cnorm[k] = s;
}

// ---------- argmin GEMM: 128 rows x 128 codes per block, D-chunks of 32 ----------
// Staging via global_load_lds (zero staging VGPRs), LDS double-buffered, one
// __syncthreads() per chunk (m97 structure). LDS LINEAR [128][32]; bank
// conflicts handled by XOR swizzle applied on BOTH the per-lane global source
// column and the ds_read index:  LDS[row][c4] holds global[row][c4 ^ (row&7)].
//
// CRITICAL (round-4 fix): the dd loop must NOT be unrolled. When unrolled, the
// compiler hoists all ~128 float4 ds_reads of a chunk, blowing the unified
// VGPR+AGPR file to 256+256 (1 wave/SIMD) and spilling ~48 GB to scratch
// (round-3 counters: WRITE_SIZE 4.8e7 KB, occupancy 12%). With unroll 1 the
// live set is acc[64] + za[32] + ca[32] + addressing ~= 145 regs -> no spill.
#define BM 128
#define BK 128
#define DC 32

typedef const __attribute__((address_space(1))) unsigned int gu32;
typedef __attribute__((address_space(3))) unsigned int lu32;

__device__ __forceinline__ void gld_lds16(const float* g, float* l) {
    __builtin_amdgcn_global_load_lds((gu32*)g, (lu32*)l, 16, 0, 0);
}

__global__ __launch_bounds__(256)
void argmin_kernel(const float* __restrict__ z,   // [NROWS,512] contiguous
                   const float* __restrict__ cb,  // [K,512]
                   const float* __restrict__ cnorm,
                   unsigned long long* __restrict__ minpack, int K) {
    __shared__ float zs[2][BM * DC];   // 2 x 16 KB
    __shared__ float ks[2][BK * DC];   // 2 x 16 KB
    const int t = threadIdx.x;
    const int w = t >> 6;              // wave id 0..3
    const int l = t & 63;              // lane
    const int rowBase = blockIdx.y * BM;
    const int kBase = blockIdx.x * BK;
    const int tx = t & 15, ty = t >> 4;

    // Staging geometry: wave w, issue u covers tile rows w*8 + 32u + (l>>3);
    // lane l's 16B lands at LDS slot c4 = l&7 of that row. Source column is
    // pre-permuted so the LDS swizzle invariant holds:
    //   c4src = (l&7) ^ (l>>3)     [row&7 == l>>3 since (w*8 + 32u) % 8 == 0]
    const int srow = l >> 3;
    const int sc4 = (l & 7) ^ srow;
    const float* zg = z + (size_t)(rowBase + w * 8 + srow) * DTOT + sc4 * 4;
    const float* kg = cb + (size_t)(kBase + w * 8 + srow) * DTOT + sc4 * 4;

    float acc[8][8];
    #pragma unroll
    for (int i = 0; i < 8; i++)
        #pragma unroll
        for (int j = 0; j < 8; j++) acc[i][j] = 0.0f;

    // prologue: stage chunk 0 into buffer 0
    #pragma unroll
    for (int u = 0; u < 4; u++) {
        gld_lds16(zg + u * (32 * DTOT), &zs[0][(w * 8 + u * 32) * DC]);
        gld_lds16(kg + u * (32 * DTOT), &ks[0][(w * 8 + u * 32) * DC]);
    }

    int buf = 0;
    for (int dc = 0; dc < DTOT; dc += DC, buf ^= 1) {
        // drains the staging of `buf` (compiler inserts vmcnt(0) before the
        // barrier) and ensures every wave finished computing on buf^1
        __syncthreads();
        if (dc + DC < DTOT) {
            // issue next chunk into the other buffer; overlaps with compute
            #pragma unroll
            for (int u = 0; u < 4; u++) {
                gld_lds16(zg + (dc + DC) + u * (32 * DTOT),
                          &zs[buf ^ 1][(w * 8 + u * 32) * DC]);
                gld_lds16(kg + (dc + DC) + u * (32 * DTOT),
                          &ks[buf ^ 1][(w * 8 + u * 32) * DC]);
            }
        }
        #pragma unroll 1   // DO NOT unroll: prevents whole-chunk ds_read hoist
        for (int dd = 0; dd < DC; dd += 4) {
            const int xz4 = ((dd >> 2) ^ (ty & 7)) * 4;   // read-side XOR (z rows)
            const int xk4 = ((dd >> 2) ^ (tx & 7)) * 4;   // read-side XOR (cb rows)
            float4 za[8];
            #pragma unroll
            for (int i = 0; i < 8; i++)
                za[i] = *(const float4*)&zs[buf][(ty + 16 * i) * DC + xz4];
            #pragma unroll
            for (int j = 0; j < 8; j++) {
                float4 ca = *(const float4*)&ks[buf][(tx + 16 * j) * DC + xk4];
                #pragma unroll
                for (int i = 0; i < 8; i++)
                    acc[i][j] += za[i].x*ca.x + za[i].y*ca.y + za[i].z*ca.z + za[i].w*ca.w;
            }
        }
    }

    float cn[8];
    #pragma unroll
    for (int j = 0; j < 8; j++) cn[j] = cnorm[kBase + tx + 16 * j];

    #pragma unroll
    for (int i = 0; i < 8; i++) {
        unsigned long long best = ~0ull;
        #pragma unroll
        for (int j = 0; j < 8; j++) {
            float s = cn[j] - 2.0f * acc[i][j];
            unsigned long long p = ((unsigned long long)fkey(s) << 32)
                                 | (unsigned int)(kBase + tx + 16 * j);
            if (p < best) best = p;
        }
        #pragma unroll
        for (int off = 8; off; off >>= 1) {
            unsigned long long o = __shfl_xor(best, off, 16);
            if (o < best) best = o;
        }
        if (tx == 0) atomicMin(&minpack[rowBase + ty + 16 * i], best);
    }
}

// ---------- extract idx (as float) ----------
__global__ void extract_kernel(const unsigned long long* __restrict__ mp,
                               float* __restrict__ out_idx) {
    int i = blockIdx.x * 256 + threadIdx.x;
    out_idx[i] = (float)(unsigned int)(mp[i] & 0xffffffffull);
}

// ---------- per-row scatter: zq write, loss, counts, pair counts, embed_sum ----------
__launch_bounds__(256)
__global__ void scatter_kernel(const float* __restrict__ zr, const float* __restrict__ zi,
                               const float* __restrict__ cb, const int* __restrict__ prev_idx,
                               const float* __restrict__ idx_f,
                               float* __restrict__ zq, float* __restrict__ embed,
                               float* __restrict__ counts, float* __restrict__ adj,
                               double* __restrict__ loss_slots, int K) {
    const int wave = threadIdx.x >> 6, lane = threadIdx.x & 63;
    const int n = blockIdx.x * 4 + wave;
    const int idx = (int)idx_f[n];
    const float* zrrow = zr + (size_t)n * HALF_D;
    const float* zirow = zi + (size_t)n * HALF_D;
    const float* crow = cb + (size_t)idx * DTOT;
    float* zqrow = zq + (size_t)n * DTOT;
    const int d0 = lane * 4;

    float4 z0 = *(const float4*)(zrrow + d0);
    float4 z1 = *(const float4*)(zirow + d0);
    float4 c0 = *(const float4*)(crow + d0);
    float4 c1 = *(const float4*)(crow + HALF_D + d0);

    float4 q0, q1;
    q0.x = z0.x + (c0.x - z0.x); q0.y = z0.y + (c0.y - z0.y);
    q0.z = z0.z + (c0.z - z0.z); q0.w = z0.w + (c0.w - z0.w);
    q1.x = z1.x + (c1.x - z1.x); q1.y = z1.y + (c1.y - z1.y);
    q1.z = z1.z + (c1.z - z1.z); q1.w = z1.w + (c1.w - z1.w);
    *(float4*)(zqrow + d0) = q0;
    *(float4*)(zqrow + HALF_D + d0) = q1;

    float dx, lsum = 0.0f;
    dx = c0.x - z0.x; lsum += dx * dx;   dx = c0.y - z0.y; lsum += dx * dx;
    dx = c0.z - z0.z; lsum += dx * dx;   dx = c0.w - z0.w; lsum += dx * dx;
    dx = c1.x - z1.x; lsum += dx * dx;   dx = c1.y - z1.y; lsum += dx * dx;
    dx = c1.z - z1.z; lsum += dx * dx;   dx = c1.w - z1.w; lsum += dx * dx;

    float* erow = embed + (size_t)idx * DTOT;
    atomicAdd(erow + d0 + 0, z0.x); atomicAdd(erow + d0 + 1, z0.y);
    atomicAdd(erow + d0 + 2, z0.z); atomicAdd(erow + d0 + 3, z0.w);
    atomicAdd(erow + HALF_D + d0 + 0, z1.x); atomicAdd(erow + HALF_D + d0 + 1, z1.y);
    atomicAdd(erow + HALF_D + d0 + 2, z1.z); atomicAdd(erow + HALF_D + d0 + 3, z1.w);

    #pragma unroll
    for (int off = 32; off; off >>= 1) lsum += __shfl_down(lsum, off, 64);
    if (lane == 0) {
        atomicAdd(&loss_slots[blockIdx.x & 255], (double)lsum);
        atomicAdd(&counts[idx], 1.0f);
        int p = prev_idx[n];
        atomicAdd(&adj[(size_t)p * K + idx], 1.0f);
    }
}

// ---------- cluster-size EMA + cs normalizer ----------
__global__ void cs_kernel(const float* __restrict__ cl, const float* __restrict__ counts,
                          float* __restrict__ cs, int K) {
    __shared__ float red[1024];
    int t = threadIdx.x;
    float s = 0.0f;
    for (int k = t; k < K; k += 1024) {
        float v = cl[k] * 0.99f + ONE_M * counts[k];
        cs[k] = v;
        s += v;
    }
    red[t] = s;
    __syncthreads();
    for (int off = 512; off; off >>= 1) {
        if (t < off) red[t] += red[t + off];
        __syncthreads();
    }
    float n = red[0];
    float keps = (float)((double)K * 1e-6);
    for (int k = t; k < K; k += 1024)
        cs[k] = (cs[k] + 1e-6f) / (n + keps) * n;
}

// ---------- codebook finalize: cb = (avg*0.99 + 0.01*embed_sum)/cs ----------
__global__ void cbfin_kernel(const float* __restrict__ avg, const float* __restrict__ cs,
                             float* __restrict__ cbout, int total) {
    int i = blockIdx.x * 256 + threadIdx.x;
    if (i < total) {
        float v = avg[i] * 0.99f + ONE_M * cbout[i];   // cbout currently holds embed_sum
        cbout[i] = v / cs[i >> 9];
    }
}

// ---------- adjacency decay transform (in-place over pair counts) ----------
__global__ void adj_kernel(const float* __restrict__ adj_in, float* __restrict__ adjout,
                           int total) {
    int i = blockIdx.x * 256 + threadIdx.x;
    if (i < total) {
        float c = adjout[i];                 // pair count
        float p = exp2f(c * LOG2_099);       // 0.99^c
        adjout[i] = adj_in[i] * p + (1.0f - p) / ONE_M;
    }
}

// ---------- loss finalize ----------
__global__ void loss_kernel(const double* __restrict__ slots, float* __restrict__ out) {
    __shared__ double red[256];
    int t = threadIdx.x;
    red[t] = slots[t] + slots[256 + t];
    __syncthreads();
    for (int off = 128; off; off >>= 1) {
        if (t < off) red[t] += red[t + off];
        __syncthreads();
    }
    if (t == 0) out[0] = (float)(1.25 * red[0] / 16777216.0);
}

extern "C" void kernel_launch(void* const* d_in, const int* in_sizes, int n_in,
                              void* d_out, int out_size, void* d_ws, size_t ws_size,
                              hipStream_t stream) {
    const float* zfr = (const float*)d_in[0];
    const float* zfi = (const float*)d_in[1];
    const float* zsr = (const float*)d_in[2];
    const float* zsi = (const float*)d_in[3];
    const int* prev_syn = (const int*)d_in[4];
    const int* prev_sem = (const int*)d_in[5];
    const float* cb_syn = (const float*)d_in[6];
    const float* cb_sem = (const float*)d_in[7];
    const float* cl_syn = (const float*)d_in[8];
    const float* avg_syn = (const float*)d_in[9];
    const float* cl_sem = (const float*)d_in[10];
    const float* avg_sem = (const float*)d_in[11];
    const float* adj_syn_in = (const float*)d_in[12];
    const float* adj_sem_in = (const float*)d_in[13];

    float* out = (float*)d_out;
    size_t o = 0;
    float* zq_syn = out + o;  o += (size_t)NROWS * DTOT;
    float* zq_sem = out + o;  o += (size_t)NROWS * DTOT;
    float* loss_out = out + o; o += 1;
    float* idx_syn = out + o; o += NROWS;
    float* idx_sem = out + o; o += NROWS;
    float* cbo_syn = out + o; o += (size_t)KSYN * DTOT;
    float* cbo_sem = out + o; o += (size_t)KSEM * DTOT;
    float* adjo_syn = out + o; o += (size_t)KSYN * KSYN;
    float* adjo_sem = out + o; o += (size_t)KSEM * KSEM;

    // small scratch in ws (64 KB)
    char* ws = (char*)d_ws;
    float* counts_syn = (float*)(ws + 0);        // 1024 f32
    float* counts_sem = (float*)(ws + 4096);     // 4096 f32
    float* cs_syn     = (float*)(ws + 20480);    // 1024 f32
    float* cs_sem     = (float*)(ws + 24576);    // 4096 f32
    float* cn_syn     = (float*)(ws + 40960);    // 1024 f32
    float* cn_sem     = (float*)(ws + 45056);    // 4096 f32
    double* loss_slots = (double*)(ws + 61440);  // 256 (syn) + 256 (sem) doubles

    // zcat buffers live in the zq output regions (exact size match);
    // consumed by argmin before scatter overwrites them with zq.
    float* zcat_syn = zq_syn;
    float* zcat_sem = zq_sem;
    // minpack lives in the head of adjo_sem; adjo_sem's FLOAT offset is odd, so
    // round up to the next 8-byte boundary for the 64-bit atomics (the round-2
    // crash was a misaligned atomicMin_u64). adj memset happens AFTER extract.
    unsigned long long* mp_syn =
        (unsigned long long*)(((uintptr_t)adjo_sem + 7) & ~(uintptr_t)7);
    unsigned long long* mp_sem = mp_syn + NROWS;

    hipMemsetAsync(d_ws, 0, 65536, stream);
    hipMemsetAsync((void*)mp_syn, 0xFF, (size_t)2 * NROWS * sizeof(unsigned long long), stream);
    hipMemsetAsync((void*)cbo_syn, 0,
                   ((size_t)KSYN * DTOT + (size_t)KSEM * DTOT) * sizeof(float), stream);

    zcat_kernel<<<NROWS * 128 / 256, 256, 0, stream>>>(zfr, zfi, zcat_syn);
    zcat_kernel<<<NROWS * 128 / 256, 256, 0, stream>>>(zsr, zsi, zcat_sem);

    cnorm_kernel<<<KSYN, 64, 0, stream>>>(cb_syn, cn_syn);
    cnorm_kernel<<<KSEM, 64, 0, stream>>>(cb_sem, cn_sem);

    argmin_kernel<<<dim3(KSYN / BK, NROWS / BM), 256, 0, stream>>>(
        zcat_syn, cb_syn, cn_syn, mp_syn, KSYN);
    argmin_kernel<<<dim3(KSEM / BK, NROWS / BM), 256, 0, stream>>>(
        zcat_sem, cb_sem, cn_sem, mp_sem, KSEM);

    extract_kernel<<<NROWS / 256, 256, 0, stream>>>(mp_syn, idx_syn);
    extract_kernel<<<NROWS / 256, 256, 0, stream>>>(mp_sem, idx_sem);

    // now safe to zero the adjacency accumulators (minpack already consumed)
    hipMemsetAsync((void*)adjo_syn, 0,
                   ((size_t)KSYN * KSYN + (size_t)KSEM * KSEM) * sizeof(float), stream);

    scatter_kernel<<<NROWS / 4, 256, 0, stream>>>(
        zfr, zfi, cb_syn, prev_syn, idx_syn, zq_syn, cbo_syn, counts_syn, adjo_syn,
        loss_slots, KSYN);
    scatter_kernel<<<NROWS / 4, 256, 0, stream>>>(
        zsr, zsi, cb_sem, prev_sem, idx_sem, zq_sem, cbo_sem, counts_sem, adjo_sem,
        loss_slots + 256, KSEM);

    cs_kernel<<<1, 1024, 0, stream>>>(cl_syn, counts_syn, cs_syn, KSYN);
    cs_kernel<<<1, 1024, 0, stream>>>(cl_sem, counts_sem, cs_sem, KSEM);

    cbfin_kernel<<<(KSYN * DTOT) / 256, 256, 0, stream>>>(avg_syn, cs_syn, cbo_syn, KSYN * DTOT);
    cbfin_kernel<<<(KSEM * DTOT) / 256, 256, 0, stream>>>(avg_sem, cs_sem, cbo_sem, KSEM * DTOT);

    adj_kernel<<<(KSYN * KSYN) / 256, 256, 0, stream>>>(adj_syn_in, adjo_syn, KSYN * KSYN);
    adj_kernel<<<(KSEM * KSEM) / 256, 256, 0, stream>>>(adj_sem_in, adjo_sem, KSEM * KSEM);

    loss_kernel<<<1, 256, 0, stream>>>(loss_slots, loss_out);
}